// Round 2
// baseline (366.622 us; speedup 1.0000x reference)
//
#include <hip/hip_runtime.h>

// Problem: B=4, M_IN=16, M_OUT=32, C=32
// x: (B, M_IN, C, C, C, C) fp32, 67,108,864 elements = 256 MiB
// out[b,n,i,c] = sum_m s_i[b,m,c] * W[m,n],  W = alpha+beta+gamma+delta
//   s_0 = s_1 = x.sum(axes 3,4,5)  (keeps c2)
//   s_2       = x.sum(axes 2,4,5)  (keeps c3)
//   s_3       = x.sum(axes 2,3,5)  (keeps c4)
//
// reduce_k: one block per (b,m,c2) slab (2048 blocks). Each WAVE owns 8 c3
//   rows (4 KiB per wave-iteration, 4 float4/lane) so the 64-lane butterfly
//   runs once per c3 total (not once per c3 per wave): DS-pipe ops per block
//   drop 768 -> ~240, VALU/byte ~2.5x lower. Plain block-exclusive stores:
//     p3[bid*32 + c3] = partial of s3 over this c2   (65536 floats)
//     p4[bid*32 + c4] = partial of s4 over this c2   (65536 floats)
//   s1 is NOT stored: s1[bid] == sum_c3 p3[bid*32+c3], folded into finalize.
// finalize_k: 16 blocks = (b, i4); reduces partials over the dead index
//   (L2-resident, 64 KB per block) into LDS, applies W, writes out.
//
// ws floats: p3[0..65536) | p4[65536..131072)  (= 512 KB)

#define P3_OFF 0
#define P4_OFF 65536

__global__ __launch_bounds__(256) void reduce_k(const float* __restrict__ x,
                                                float* __restrict__ ws) {
    const int t    = threadIdx.x;       // 0..255
    const int bid  = blockIdx.x;        // (bm<<5) | c2 ; bm = b*16+m
    const int lane = t & 63;
    const int wv   = t >> 6;            // wave id 0..3

    __shared__ float lds4[4][32];       // per-wave c4 partials

    // Slab = 32768 floats = 8192 float4. Wave wv owns c3 = wv*8 .. wv*8+7,
    // i.e. float4s [wv*2048, wv*2048+2048).
    const float4* xv = (const float4*)x + (size_t)bid * 8192 + wv * 2048;

    float acc0 = 0.f, acc1 = 0.f, acc2 = 0.f, acc3 = 0.f;  // c4 partials

    #pragma unroll 2
    for (int it = 0; it < 8; ++it) {    // c3 = wv*8 + it
        const float4* row = xv + it * 256;   // 1024 floats for this c3
        float4 f0 = row[lane];
        float4 f1 = row[lane + 64];
        float4 f2 = row[lane + 128];
        float4 f3 = row[lane + 192];
        float v0 = (f0.x + f0.y) + (f0.z + f0.w);
        float v1 = (f1.x + f1.y) + (f1.z + f1.w);
        float v2 = (f2.x + f2.y) + (f2.z + f2.w);
        float v3 = (f3.x + f3.y) + (f3.z + f3.w);
        // c4 of v_j for this lane: (lane>>3) + 8*j  (constant across it)
        acc0 += v0; acc1 += v1; acc2 += v2; acc3 += v3;
        // s3[c3]: one butterfly per c3, owned by this wave alone
        float s = (v0 + v1) + (v2 + v3);
        #pragma unroll
        for (int off = 1; off < 64; off <<= 1)
            s += __shfl_xor(s, off, 64);
        if (lane == 0)
            ws[P3_OFF + bid * 32 + wv * 8 + it] = s;   // exclusive plain store
    }

    // s4: reduce acc_j over the 8 lanes sharing lane>>3 (3 shuffles each)
    #pragma unroll
    for (int off = 1; off < 8; off <<= 1) {
        acc0 += __shfl_xor(acc0, off, 64);
        acc1 += __shfl_xor(acc1, off, 64);
        acc2 += __shfl_xor(acc2, off, 64);
        acc3 += __shfl_xor(acc3, off, 64);
    }
    if ((lane & 7) == 0) {
        int g = lane >> 3;              // 0..7
        lds4[wv][g]      = acc0;
        lds4[wv][g + 8]  = acc1;
        lds4[wv][g + 16] = acc2;
        lds4[wv][g + 24] = acc3;
    }
    __syncthreads();

    if (t < 32)
        ws[P4_OFF + bid * 32 + t] =
            lds4[0][t] + lds4[1][t] + lds4[2][t] + lds4[3][t];
}

__global__ __launch_bounds__(256) void finalize_k(const float* __restrict__ ws,
                                                  const float* __restrict__ alpha,
                                                  const float* __restrict__ beta,
                                                  const float* __restrict__ gamma,
                                                  const float* __restrict__ delta,
                                                  float* __restrict__ out) {
    __shared__ float W[512];            // W[m*32+n] = sum of the 4 weight mats
    __shared__ float S[16][32];         // S[m][c] = s_{i4}[b][m][c]
    const int t  = threadIdx.x;
    const int b  = blockIdx.x >> 2;     // 0..3
    const int i4 = blockIdx.x & 3;      // 0..3

    #pragma unroll
    for (int i = t; i < 512; i += 256)
        W[i] = alpha[i] + beta[i] + gamma[i] + delta[i];

    if (i4 <= 1) {
        // s1 == s2 = sum_c3 p3[(bm,c2),c3]: 32 consecutive floats per (m,c2)
        #pragma unroll
        for (int i = t; i < 512; i += 256) {
            int m = i >> 5, c = i & 31;
            const float* q = ws + P3_OFF + (b * 16 + m) * 1024 + c * 32;
            float acc = 0.0f;
            #pragma unroll
            for (int k = 0; k < 32; ++k)
                acc += q[k];
            S[m][c] = acc;
        }
    } else {
        // reduce p3/p4 over c2 (stride-32 gather; 64 KB, L2-resident)
        const float* p = ws + (i4 == 2 ? P3_OFF : P4_OFF);
        #pragma unroll
        for (int i = t; i < 512; i += 256) {
            int m = i >> 5, c = i & 31;
            const float* q = p + (b * 16 + m) * 1024 + c;   // + c2*32 below
            float acc = 0.0f;
            #pragma unroll
            for (int c2 = 0; c2 < 32; ++c2)
                acc += q[c2 * 32];
            S[m][c] = acc;
        }
    }
    __syncthreads();

    // 1024 outputs per block: out[b, n, i4, c] for all (n, c)
    #pragma unroll
    for (int k = 0; k < 4; ++k) {
        int idx = k * 256 + t;          // 0..1023
        int n = idx >> 5, c = idx & 31; // n broadcast per 32 lanes, c coalesced
        float acc = 0.0f;
        #pragma unroll
        for (int m = 0; m < 16; ++m)
            acc += S[m][c] * W[m * 32 + n];
        out[((b * 32 + n) * 4 + i4) * 32 + c] = acc;
    }
}

extern "C" void kernel_launch(void* const* d_in, const int* in_sizes, int n_in,
                              void* d_out, int out_size, void* d_ws, size_t ws_size,
                              hipStream_t stream) {
    const float* x     = (const float*)d_in[0];
    const float* alpha = (const float*)d_in[1];
    const float* beta  = (const float*)d_in[2];
    const float* gamma = (const float*)d_in[3];
    const float* delta = (const float*)d_in[4];
    float* out = (float*)d_out;
    float* ws  = (float*)d_ws;

    reduce_k<<<2048, 256, 0, stream>>>(x, ws);    // streaming pass, plain stores
    finalize_k<<<16, 256, 0, stream>>>(ws, alpha, beta, gamma, delta, out);
}